// Round 3
// baseline (208.697 us; speedup 1.0000x reference)
//
#include <hip/hip_runtime.h>

// ModularPathwayConv round 13:
//  R12 post-mortem: fusion kept (+2us), ticket revert confirmed (-27us).
//  Budget: fill 44 (fixed) + hist 38 + precomp 17 + scatter 38 + accum 45.
//  1. hist_rank || precompute-tiles fused into ONE grid (independent inputs;
//     hist latency-bound, tiles MFMA-bound -> co-scheduled). Hist threads do
//     4 edges each (4 independent atomic chains) to keep atomic MLP at the
//     merged kernel's lower occupancy. Scan -> own tiny kernel.
//  2. scatter srp writes -> nontemporal (cross-XCD false-sharing of 64B srp
//     lines caused 55MB WRITE_SIZE on a 3.2MB array).
//  Dispatches: memset -> hist+tiles -> scan -> scatter -> accum_final.

constexpr int TPB = 256;

typedef __attribute__((ext_vector_type(8))) short short8;
typedef __attribute__((ext_vector_type(4))) float f32x4;
typedef __attribute__((ext_vector_type(2))) float f32x2;

// fp32 -> bf16 round-to-nearest-even
__device__ inline unsigned short f2bf(float f) {
  unsigned u = __float_as_uint(f);
  unsigned r = u + 0x7fffu + ((u >> 16) & 1u);
  return (unsigned short)(r >> 16);
}

// ---- fp8 e4m3 encode/decode (HW builtins when available) ----
#if __has_builtin(__builtin_amdgcn_cvt_pk_fp8_f32) && __has_builtin(__builtin_amdgcn_cvt_pk_f32_fp8)
#define FP8_HW 1
#else
#define FP8_HW 0
#endif

__device__ inline unsigned f32_to_fp8(float f) {
#if FP8_HW
  return (unsigned)__builtin_amdgcn_cvt_pk_fp8_f32(f, f, 0, false) & 0xFFu;
#else
  unsigned u = __float_as_uint(f);
  unsigned s = u >> 31;
  float af = fabsf(f);
  if (af >= 448.f) return (s << 7) | 0x7E;
  if (af < 0.015625f) {
    int m = (int)(af * 512.0f + 0.5f);
    if (m > 7) m = 7;
    return (s << 7) | m;
  }
  unsigned r = (u & 0x7FFFFFFFu) + 0x7FFFFu + ((u >> 20) & 1u);
  int e = (int)((r >> 23) & 0xFF) - 127 + 7;
  if (e >= 16) return (s << 7) | 0x7E;
  return (s << 7) | ((unsigned)e << 3) | ((r >> 20) & 7);
#endif
}

// decode 4 fp8 packed in a u32 -> 4 floats
__device__ inline void fp8x4_to_f32(unsigned w, float* o) {
#if FP8_HW
  f32x2 lo = __builtin_amdgcn_cvt_pk_f32_fp8((int)w, false);
  f32x2 hi = __builtin_amdgcn_cvt_pk_f32_fp8((int)w, true);
  o[0] = lo[0]; o[1] = lo[1]; o[2] = hi[0]; o[3] = hi[1];
#else
#pragma unroll
  for (int i = 0; i < 4; ++i) {
    unsigned b = (w >> (8 * i)) & 0xFF;
    unsigned s = (b >> 7) & 1, e = (b >> 3) & 0xF, m = b & 7;
    float v;
    if (e == 0) { v = (float)m * 0.001953125f; v = s ? -v : v; }
    else v = __uint_as_float((s << 31) | ((e - 7 + 127) << 23) | (m << 20));
    o[i] = v;
  }
#endif
}

// ---------------- fused: histogram+rank || precompute MFMA ----------------
// Blocks [0, hb): hist, 4 edges/thread (4 independent atomic chains).
// Blocks [hb, hb+tblocks): A = x@W1_top (fp8), Bp = x@W1_bot + b1 (bf16).

__global__ __launch_bounds__(TPB) void hist_and_precompute(
    const int* __restrict__ ei, int* __restrict__ cnt, int* __restrict__ rank,
    int E, const float* __restrict__ x, const float* __restrict__ W1,
    const float* __restrict__ b1, unsigned char* __restrict__ Af8,
    unsigned short* __restrict__ Bpbf, int N, int hb)
{
  if ((int)blockIdx.x < hb) {
    const int base = blockIdx.x * (TPB * 4) + (int)threadIdx.x;
#pragma unroll
    for (int k = 0; k < 4; ++k) {
      const int e = base + k * TPB;
      if (e < E) rank[e] = atomicAdd(&cnt[ei[E + e]], 1);
    }
    return;
  }

  // ---- precompute tiles ----
  __shared__ __align__(16) unsigned short sFrag[8 * 2 * 64 * 8];   // 16 KB

  for (int idx = threadIdx.x; idx < 8192; idx += TPB) {
    const int j  = idx & 7;
    const int l  = (idx >> 3) & 63;
    const int ks = (idx >> 9) & 1;
    const int ct = idx >> 10;
    const int k  = ks * 32 + ((l >> 4) << 3) + j;
    const int r  = k + 64 * (ct >> 2);
    const int c  = (ct & 3) * 16 + (l & 15);
    sFrag[idx] = f2bf(W1[r * 64 + c]);
  }
  __syncthreads();

  const int w = threadIdx.x >> 6;
  const int l = threadIdx.x & 63;
  const int q = l >> 4;
  const int m = l & 15;
  const int n0 = (((int)blockIdx.x - hb) * 4 + w) * 16;
  if (n0 >= N) return;

  short8 bfrag[8][2];
#pragma unroll
  for (int ct = 0; ct < 8; ++ct)
#pragma unroll
    for (int ks = 0; ks < 2; ++ks)
      bfrag[ct][ks] =
          *reinterpret_cast<const short8*>(&sFrag[(ct * 2 + ks) * 512 + l * 8]);

  const int nA = (n0 + m < N) ? (n0 + m) : (N - 1);
  const float* xr = x + (size_t)nA * 64 + q * 8;
  short8 afrag[2];
#pragma unroll
  for (int ks = 0; ks < 2; ++ks) {
    float4 v0 = *reinterpret_cast<const float4*>(xr + ks * 32);
    float4 v1 = *reinterpret_cast<const float4*>(xr + ks * 32 + 4);
    short8 a;
    a[0] = (short)f2bf(v0.x); a[1] = (short)f2bf(v0.y);
    a[2] = (short)f2bf(v0.z); a[3] = (short)f2bf(v0.w);
    a[4] = (short)f2bf(v1.x); a[5] = (short)f2bf(v1.y);
    a[6] = (short)f2bf(v1.z); a[7] = (short)f2bf(v1.w);
    afrag[ks] = a;
  }

  f32x4 acc[8];
#pragma unroll
  for (int ct = 0; ct < 8; ++ct) {
    const float bv = (ct >= 4) ? b1[(ct - 4) * 16 + m] : 0.0f;
    acc[ct] = (f32x4){bv, bv, bv, bv};
  }

#pragma unroll
  for (int ct = 0; ct < 8; ++ct)
#pragma unroll
    for (int ks = 0; ks < 2; ++ks)
      acc[ct] = __builtin_amdgcn_mfma_f32_16x16x32_bf16(
          afrag[ks], bfrag[ct][ks], acc[ct], 0, 0, 0);

#pragma unroll
  for (int ct = 0; ct < 8; ++ct) {
    const int ch = (ct & 3) * 16 + m;
#pragma unroll
    for (int r = 0; r < 4; ++r) {
      const int node = n0 + q * 4 + r;
      if (node >= N) continue;
      if (ct < 4)
        Af8[(size_t)node * 64 + ch] = (unsigned char)f32_to_fp8(acc[ct][r]);
      else
        Bpbf[(size_t)node * 64 + ch] = f2bf(acc[ct][r]);
    }
  }
}

// ---------------- CSR base assignment (block scan + atomic ticket) --------

__global__ __launch_bounds__(TPB) void scan_bases(
    const int* __restrict__ cnt, int* __restrict__ off,
    int* __restrict__ total, int N)
{
  __shared__ int sScan[TPB];
  __shared__ int sBase;
  const int i = blockIdx.x * TPB + (int)threadIdx.x;
  const int v = (i < N) ? cnt[i] : 0;
  sScan[threadIdx.x] = v;
  __syncthreads();
  for (int d = 1; d < TPB; d <<= 1) {
    int t = ((int)threadIdx.x >= d) ? sScan[threadIdx.x - d] : 0;
    __syncthreads();
    sScan[threadIdx.x] += t;
    __syncthreads();
  }
  if (threadIdx.x == TPB - 1) sBase = atomicAdd(total, sScan[TPB - 1]);
  __syncthreads();
  if (i < N) off[i] = sBase + sScan[threadIdx.x] - v;
}

// atomic-free scatter with 4B packed record: (row << 15) | q15(ea)
// NT store: srp lines are false-shared across XCDs; bypass L2 ownership.
__global__ void scatter_edges(const int* __restrict__ ei, const float* __restrict__ ea,
                              const int* __restrict__ off, const int* __restrict__ rank,
                              unsigned int* __restrict__ srp, int E) {
  int e = blockIdx.x * blockDim.x + threadIdx.x;
  if (e >= E) return;
  int col = ei[E + e];
  int pos = off[col] + rank[e];
  unsigned q = (unsigned)(ea[e] * 32767.0f + 0.5f);
  if (q > 32767u) q = 32767u;
  __builtin_nontemporal_store(((unsigned)ei[e] << 15) | q, &srp[pos]);
}

// ---------------- fused accumulate + final GEMM ----------------
// Phase 1 (4 lanes/node, 64 nodes/block): H[n] = sum relu(ea*A[row]+Bp[n]),
// bf16-packed into an XOR-swizzled 8KB LDS tile (no Hbf round-trip).
// Phase 2: out = H @ W2 + deg*b2 via mfma_f32_16x16x32_bf16 on the LDS tile.

__global__ __launch_bounds__(TPB) void accum_final(
    const unsigned char* __restrict__ Af8, const unsigned int* __restrict__ Bpbf,
    const unsigned int* __restrict__ srp, const int* __restrict__ off,
    const int* __restrict__ cnt, const float* __restrict__ W2,
    const float* __restrict__ b2, float* __restrict__ out, int N)
{
  __shared__ __align__(16) unsigned short sW[4 * 2 * 64 * 8];   // 8 KB W2 frags
  __shared__ __align__(16) unsigned short sH[64 * 64];          // 8 KB H tile

  // ---- stage W2 fragments ----
  for (int idx = threadIdx.x; idx < 4096; idx += TPB) {
    const int j  = idx & 7;
    const int l  = (idx >> 3) & 63;
    const int ks = (idx >> 9) & 1;
    const int ct = idx >> 10;
    const int k  = ks * 32 + ((l >> 4) << 3) + j;
    const int c  = ct * 16 + (l & 15);
    sW[idx] = f2bf(W2[k * 64 + c]);
  }

  // ---- phase 1: accumulate H for this block's 64 nodes ----
  const int tid = (int)threadIdx.x;
  const int nl  = tid >> 2;            // local node 0..63
  const int q   = tid & 3;             // channel quad (16 ch/lane)
  const int n   = blockIdx.x * 64 + nl;
  const bool valid = (n < N);

  int start = 0, deg = 0;
  float bpf[16];
  if (valid) {
    start = off[n];
    deg   = cnt[n];
    const uint4* brow = reinterpret_cast<const uint4*>(Bpbf) + (size_t)n * 8 + q * 2;
    uint4 b0 = brow[0], b1v = brow[1];
    const unsigned int bu[8] = {b0.x, b0.y, b0.z, b0.w, b1v.x, b1v.y, b1v.z, b1v.w};
#pragma unroll
    for (int j = 0; j < 8; ++j) {
      bpf[2 * j]     = __uint_as_float(bu[j] << 16);
      bpf[2 * j + 1] = __uint_as_float(bu[j] & 0xffff0000u);
    }
  } else {
#pragma unroll
    for (int j = 0; j < 16; ++j) bpf[j] = 0.f;
  }

  float acc[16];
#pragma unroll
  for (int j = 0; j < 16; ++j) acc[j] = 0.f;

  // 4-deep chunks: 4 packed records + 4 independent 16B A-loads in flight
  for (int t0 = 0; t0 < deg; t0 += 4) {
    const int rem = deg - t0;
    unsigned er[4];
#pragma unroll
    for (int i = 0; i < 4; ++i)
      er[i] = (i < rem) ? srp[start + t0 + i] : 0u;

    uint4 Av[4];
#pragma unroll
    for (int i = 0; i < 4; ++i) {
      const size_t row = (size_t)(er[i] >> 15);
      Av[i] = *reinterpret_cast<const uint4*>(Af8 + row * 64 + q * 16);
    }

#pragma unroll
    for (int i = 0; i < 4; ++i) {
      if (i >= rem) break;
      const float eav = (float)(er[i] & 0x7FFFu) * (1.0f / 32767.0f);
      float a[16];
      fp8x4_to_f32(Av[i].x, a);
      fp8x4_to_f32(Av[i].y, a + 4);
      fp8x4_to_f32(Av[i].z, a + 8);
      fp8x4_to_f32(Av[i].w, a + 12);
#pragma unroll
      for (int j = 0; j < 16; ++j)
        acc[j] += fmaxf(fmaf(eav, a[j], bpf[j]), 0.f);
    }
  }

  // pack 16 fp32 -> bf16, store 2x16B into swizzled LDS row
  {
    uint4 h0, h1;
    unsigned int* h0w = &h0.x;
    unsigned int* h1w = &h1.x;
#pragma unroll
    for (int j = 0; j < 4; ++j) {
      h0w[j] = (unsigned int)f2bf(acc[2 * j]) |
               ((unsigned int)f2bf(acc[2 * j + 1]) << 16);
      h1w[j] = (unsigned int)f2bf(acc[8 + 2 * j]) |
               ((unsigned int)f2bf(acc[8 + 2 * j + 1]) << 16);
    }
    const int swz = (nl & 7) << 3;
    *reinterpret_cast<uint4*>(&sH[(nl * 64 + q * 16) ^ swz])     = h0;
    *reinterpret_cast<uint4*>(&sH[(nl * 64 + q * 16 + 8) ^ swz]) = h1;
  }

  __syncthreads();

  // ---- phase 2: out tile = H @ W2 + deg*b2 (wave w -> 16-node subtile) ----
  const int w  = tid >> 6;
  const int l  = tid & 63;
  const int q2 = l >> 4;
  const int m  = l & 15;
  const int n0 = blockIdx.x * 64 + w * 16;
  if (n0 >= N) return;

  short8 bfrag[4][2];
#pragma unroll
  for (int ct = 0; ct < 4; ++ct)
#pragma unroll
    for (int ks = 0; ks < 2; ++ks)
      bfrag[ct][ks] =
          *reinterpret_cast<const short8*>(&sW[(ct * 2 + ks) * 512 + l * 8]);

  const int row = w * 16 + m;                 // LDS row == local node
  const int rswz = (row & 7) << 3;
  short8 afrag[2];
  afrag[0] = *reinterpret_cast<const short8*>(&sH[(row * 64 + q2 * 8) ^ rswz]);
  afrag[1] = *reinterpret_cast<const short8*>(&sH[(row * 64 + 32 + q2 * 8) ^ rswz]);

  float dg[4];
#pragma unroll
  for (int r = 0; r < 4; ++r) {
    const int node = n0 + q2 * 4 + r;
    dg[r] = (node < N) ? (float)cnt[node] : 0.0f;
  }

  f32x4 acc2[4];
#pragma unroll
  for (int ct = 0; ct < 4; ++ct) {
    const float bv = b2[ct * 16 + m];
    acc2[ct] = (f32x4){dg[0] * bv, dg[1] * bv, dg[2] * bv, dg[3] * bv};
  }

#pragma unroll
  for (int ct = 0; ct < 4; ++ct)
#pragma unroll
    for (int ks = 0; ks < 2; ++ks)
      acc2[ct] = __builtin_amdgcn_mfma_f32_16x16x32_bf16(
          afrag[ks], bfrag[ct][ks], acc2[ct], 0, 0, 0);

#pragma unroll
  for (int ct = 0; ct < 4; ++ct) {
    const int ch = ct * 16 + m;
#pragma unroll
    for (int r = 0; r < 4; ++r) {
      const int node = n0 + q2 * 4 + r;
      if (node < N) out[(size_t)node * 64 + ch] = acc2[ct][r];
    }
  }
}

// ---------------- fallback (round-1 path, if ws too small) ----------------

__global__ __launch_bounds__(TPB) void edge_mlp_atomic(
    const float* __restrict__ x, const int* __restrict__ ei,
    const float* __restrict__ eattr, const float* __restrict__ W1,
    const float* __restrict__ b1, const float* __restrict__ W2,
    const float* __restrict__ b2, float* __restrict__ out, int E)
{
  __shared__ float sW1[128 * 64];
  __shared__ float sW2[64 * 64];
  __shared__ float sB1[64];
  __shared__ float sB2[64];
  for (int i = threadIdx.x; i < 128 * 64 / 4; i += TPB)
    reinterpret_cast<float4*>(sW1)[i] = reinterpret_cast<const float4*>(W1)[i];
  for (int i = threadIdx.x; i < 64 * 64 / 4; i += TPB)
    reinterpret_cast<float4*>(sW2)[i] = reinterpret_cast<const float4*>(W2)[i];
  if (threadIdx.x < 64) { sB1[threadIdx.x] = b1[threadIdx.x]; sB2[threadIdx.x] = b2[threadIdx.x]; }
  __syncthreads();
  const int e = blockIdx.x * TPB + (int)threadIdx.x;
  if (e >= E) return;
  const int row = ei[e];
  const int col = ei[E + e];
  const float scale = eattr[e];
  float h[64];
#pragma unroll
  for (int o = 0; o < 64; ++o) h[o] = sB1[o];
#pragma unroll
  for (int half = 0; half < 2; ++half) {
    const float4* src = reinterpret_cast<const float4*>(x + (size_t)(half ? col : row) * 64);
    const float sc = half ? 1.0f : scale;
    const float* wb = sW1 + half * 64 * 64;
    for (int kc = 0; kc < 16; ++kc) {
      float4 cv = src[kc];
      cv.x *= sc; cv.y *= sc; cv.z *= sc; cv.w *= sc;
      const float* wr = wb + kc * 4 * 64;
#pragma unroll
      for (int kk = 0; kk < 4; ++kk) {
        const float c = (&cv.x)[kk];
#pragma unroll
        for (int o = 0; o < 64; ++o) h[o] = fmaf(c, wr[kk * 64 + o], h[o]);
      }
    }
  }
#pragma unroll
  for (int o = 0; o < 64; ++o) h[o] = fmaxf(h[o], 0.0f);
  float* outrow = out + (size_t)col * 64;
#pragma unroll
  for (int oc = 0; oc < 4; ++oc) {
    float m[16];
#pragma unroll
    for (int j = 0; j < 16; ++j) m[j] = sB2[oc * 16 + j];
#pragma unroll
    for (int k = 0; k < 64; ++k) {
      const float hk = h[k];
      const float* wr = sW2 + k * 64 + oc * 16;
#pragma unroll
      for (int j = 0; j < 16; ++j) m[j] = fmaf(hk, wr[j], m[j]);
    }
#pragma unroll
    for (int j = 0; j < 16; ++j) atomicAdd(outrow + oc * 16 + j, m[j]);
  }
}

// ---------------- launch ----------------

extern "C" void kernel_launch(void* const* d_in, const int* in_sizes, int n_in,
                              void* d_out, int out_size, void* d_ws, size_t ws_size,
                              hipStream_t stream) {
  const float* x  = (const float*)d_in[0];
  const int*   ei = (const int*)d_in[1];   // [2,E] int32
  const float* ea = (const float*)d_in[2];
  const float* W1 = (const float*)d_in[3];
  const float* b1 = (const float*)d_in[4];
  const float* W2 = (const float*)d_in[5];
  const float* b2 = (const float*)d_in[6];
  float* out = (float*)d_out;
  const int E = in_sizes[2];
  const int N = in_sizes[0] / 64;

  // ws layout: srp[E] u32 | rank[E] | cnt[N]+total | off[N]
  //            | Af8[N*64 u8] | Bpbf[N*64 u16]
  auto align16 = [](size_t v) { return (v + 15) & ~(size_t)15; };
  size_t o_srp  = 0;
  size_t o_rank = align16(o_srp + (size_t)E * 4);
  size_t o_cnt  = align16(o_rank + (size_t)E * 4);          // cnt + total contiguous
  size_t o_off  = align16(o_cnt + (size_t)(N + 1) * 4);
  size_t o_A    = align16(o_off + (size_t)N * 4);
  size_t o_Bp   = align16(o_A + (size_t)N * 64);
  size_t need   = o_Bp + (size_t)N * 128;

  if (ws_size < need || N > (1 << 17)) {
    hipMemsetAsync(d_out, 0, (size_t)out_size * sizeof(float), stream);
    const int blocks = (E + TPB - 1) / TPB;
    edge_mlp_atomic<<<blocks, TPB, 0, stream>>>(x, ei, ea, W1, b1, W2, b2, out, E);
    return;
  }

  char* ws = (char*)d_ws;
  unsigned int* srp = (unsigned int*)(ws + o_srp);
  int*  rank  = (int*)(ws + o_rank);
  int*  cnt   = (int*)(ws + o_cnt);
  int*  total = cnt + N;
  int*  off   = (int*)(ws + o_off);
  unsigned char*  Af8  = (unsigned char*)(ws + o_A);
  unsigned short* Bpbf = (unsigned short*)(ws + o_Bp);

  hipMemsetAsync(cnt, 0, (size_t)(N + 1) * sizeof(int), stream);

  const int eblocks = (E + TPB - 1) / TPB;
  const int hb = (E + TPB * 4 - 1) / (TPB * 4);   // hist blocks (4 edges/thread)
  const int bb = (N + TPB - 1) / TPB;             // scan blocks
  const int tblocks = ((N + 15) / 16 + 3) / 4;    // precompute tiles
  const int nb = (N + 63) / 64;                   // accum_final blocks

  hist_and_precompute<<<hb + tblocks, TPB, 0, stream>>>(
      ei, cnt, rank, E, x, W1, b1, Af8, Bpbf, N, hb);
  scan_bases<<<bb, TPB, 0, stream>>>(cnt, off, total, N);
  scatter_edges<<<eblocks, TPB, 0, stream>>>(ei, ea, off, rank, srp, E);
  accum_final<<<nb, TPB, 0, stream>>>(Af8, (const unsigned int*)Bpbf,
                                      srp, off, cnt, W2, b2, out, N);
}

// Round 5
// 196.251 us; speedup vs baseline: 1.0634x; 1.0634x over previous
//
#include <hip/hip_runtime.h>

// ModularPathwayConv round 15 (= R14 resubmit; container infra failure, no
// kernel verdict).
//  R13 post-mortem: hist||precomp fusion gave ZERO overlap (57.8 ≈ 38+17
//  serial) — merged kernel's VGPR/LDS envelope cut hist's occupancy to 33%,
//  strangling the TLP that hides atomic latency. Full revert to R12 (194.3).
//  Single change vs R12: accum_final edge-loop split across 2 half-groups
//  (8 lanes/node, TPB 512). Serial gather-chain depth halves, waves double;
//  halves combine via __shfl_xor(acc,4). Phase-2 MFMA unchanged (waves 0-3).
//  5 dispatches: memset -> hist_rank -> base+precompute -> scatter -> accum.

constexpr int TPB = 256;

typedef __attribute__((ext_vector_type(8))) short short8;
typedef __attribute__((ext_vector_type(4))) float f32x4;
typedef __attribute__((ext_vector_type(2))) float f32x2;

// fp32 -> bf16 round-to-nearest-even
__device__ inline unsigned short f2bf(float f) {
  unsigned u = __float_as_uint(f);
  unsigned r = u + 0x7fffu + ((u >> 16) & 1u);
  return (unsigned short)(r >> 16);
}

// ---- fp8 e4m3 encode/decode (HW builtins when available) ----
#if __has_builtin(__builtin_amdgcn_cvt_pk_fp8_f32) && __has_builtin(__builtin_amdgcn_cvt_pk_f32_fp8)
#define FP8_HW 1
#else
#define FP8_HW 0
#endif

__device__ inline unsigned f32_to_fp8(float f) {
#if FP8_HW
  return (unsigned)__builtin_amdgcn_cvt_pk_fp8_f32(f, f, 0, false) & 0xFFu;
#else
  unsigned u = __float_as_uint(f);
  unsigned s = u >> 31;
  float af = fabsf(f);
  if (af >= 448.f) return (s << 7) | 0x7E;
  if (af < 0.015625f) {
    int m = (int)(af * 512.0f + 0.5f);
    if (m > 7) m = 7;
    return (s << 7) | m;
  }
  unsigned r = (u & 0x7FFFFFFFu) + 0x7FFFFu + ((u >> 20) & 1u);
  int e = (int)((r >> 23) & 0xFF) - 127 + 7;
  if (e >= 16) return (s << 7) | 0x7E;
  return (s << 7) | ((unsigned)e << 3) | ((r >> 20) & 7);
#endif
}

// decode 4 fp8 packed in a u32 -> 4 floats
__device__ inline void fp8x4_to_f32(unsigned w, float* o) {
#if FP8_HW
  f32x2 lo = __builtin_amdgcn_cvt_pk_f32_fp8((int)w, false);
  f32x2 hi = __builtin_amdgcn_cvt_pk_f32_fp8((int)w, true);
  o[0] = lo[0]; o[1] = lo[1]; o[2] = hi[0]; o[3] = hi[1];
#else
#pragma unroll
  for (int i = 0; i < 4; ++i) {
    unsigned b = (w >> (8 * i)) & 0xFF;
    unsigned s = (b >> 7) & 1, e = (b >> 3) & 0xF, m = b & 7;
    float v;
    if (e == 0) { v = (float)m * 0.001953125f; v = s ? -v : v; }
    else v = __uint_as_float((s << 31) | ((e - 7 + 127) << 23) | (m << 20));
    o[i] = v;
  }
#endif
}

// ---------------- CSR build (R10 form: atomic rank, atomic-free scatter) ----

__global__ void hist_rank(const int* __restrict__ ei, int* __restrict__ cnt,
                          int* __restrict__ rank, int E) {
  int e = blockIdx.x * blockDim.x + threadIdx.x;
  if (e < E) rank[e] = atomicAdd(&cnt[ei[E + e]], 1);
}

// atomic-free scatter with 4B packed record: (row << 15) | q15(ea)
__global__ void scatter_edges(const int* __restrict__ ei, const float* __restrict__ ea,
                              const int* __restrict__ off, const int* __restrict__ rank,
                              unsigned int* __restrict__ srp, int E) {
  int e = blockIdx.x * blockDim.x + threadIdx.x;
  if (e >= E) return;
  int col = ei[E + e];
  int pos = off[col] + rank[e];
  unsigned q = (unsigned)(ea[e] * 32767.0f + 0.5f);
  if (q > 32767u) q = 32767u;
  srp[pos] = ((unsigned)ei[e] << 15) | q;
}

// ---------------- fused: CSR base assignment | precompute MFMA ----------------

__global__ __launch_bounds__(TPB) void base_and_precompute(
    const float* __restrict__ x, const float* __restrict__ W1,
    const float* __restrict__ b1, const int* __restrict__ cnt,
    int* __restrict__ off, int* __restrict__ total,
    unsigned char* __restrict__ Af8, unsigned short* __restrict__ Bpbf,
    int N, int bb)
{
  if ((int)blockIdx.x < bb) {
    // ---- CSR base assignment: block-local scan + one global atomic ----
    __shared__ int sScan[TPB];
    __shared__ int sBase;
    const int i = blockIdx.x * TPB + (int)threadIdx.x;
    const int v = (i < N) ? cnt[i] : 0;
    sScan[threadIdx.x] = v;
    __syncthreads();
    for (int d = 1; d < TPB; d <<= 1) {
      int t = ((int)threadIdx.x >= d) ? sScan[threadIdx.x - d] : 0;
      __syncthreads();
      sScan[threadIdx.x] += t;
      __syncthreads();
    }
    if (threadIdx.x == TPB - 1) sBase = atomicAdd(total, sScan[TPB - 1]);
    __syncthreads();
    if (i < N) off[i] = sBase + sScan[threadIdx.x] - v;
    return;
  }

  // ---- precompute tiles ----
  __shared__ __align__(16) unsigned short sFrag[8 * 2 * 64 * 8];   // 16 KB

  for (int idx = threadIdx.x; idx < 8192; idx += TPB) {
    const int j  = idx & 7;
    const int l  = (idx >> 3) & 63;
    const int ks = (idx >> 9) & 1;
    const int ct = idx >> 10;
    const int k  = ks * 32 + ((l >> 4) << 3) + j;
    const int r  = k + 64 * (ct >> 2);
    const int c  = (ct & 3) * 16 + (l & 15);
    sFrag[idx] = f2bf(W1[r * 64 + c]);
  }
  __syncthreads();

  const int w = threadIdx.x >> 6;
  const int l = threadIdx.x & 63;
  const int q = l >> 4;
  const int m = l & 15;
  const int n0 = (((int)blockIdx.x - bb) * 4 + w) * 16;
  if (n0 >= N) return;

  short8 bfrag[8][2];
#pragma unroll
  for (int ct = 0; ct < 8; ++ct)
#pragma unroll
    for (int ks = 0; ks < 2; ++ks)
      bfrag[ct][ks] =
          *reinterpret_cast<const short8*>(&sFrag[(ct * 2 + ks) * 512 + l * 8]);

  const int nA = (n0 + m < N) ? (n0 + m) : (N - 1);
  const float* xr = x + (size_t)nA * 64 + q * 8;
  short8 afrag[2];
#pragma unroll
  for (int ks = 0; ks < 2; ++ks) {
    float4 v0 = *reinterpret_cast<const float4*>(xr + ks * 32);
    float4 v1 = *reinterpret_cast<const float4*>(xr + ks * 32 + 4);
    short8 a;
    a[0] = (short)f2bf(v0.x); a[1] = (short)f2bf(v0.y);
    a[2] = (short)f2bf(v0.z); a[3] = (short)f2bf(v0.w);
    a[4] = (short)f2bf(v1.x); a[5] = (short)f2bf(v1.y);
    a[6] = (short)f2bf(v1.z); a[7] = (short)f2bf(v1.w);
    afrag[ks] = a;
  }

  f32x4 acc[8];
#pragma unroll
  for (int ct = 0; ct < 8; ++ct) {
    const float bv = (ct >= 4) ? b1[(ct - 4) * 16 + m] : 0.0f;
    acc[ct] = (f32x4){bv, bv, bv, bv};
  }

#pragma unroll
  for (int ct = 0; ct < 8; ++ct)
#pragma unroll
    for (int ks = 0; ks < 2; ++ks)
      acc[ct] = __builtin_amdgcn_mfma_f32_16x16x32_bf16(
          afrag[ks], bfrag[ct][ks], acc[ct], 0, 0, 0);

#pragma unroll
  for (int ct = 0; ct < 8; ++ct) {
    const int ch = (ct & 3) * 16 + m;
#pragma unroll
    for (int r = 0; r < 4; ++r) {
      const int node = n0 + q * 4 + r;
      if (node >= N) continue;
      if (ct < 4)
        Af8[(size_t)node * 64 + ch] = (unsigned char)f32_to_fp8(acc[ct][r]);
      else
        Bpbf[(size_t)node * 64 + ch] = f2bf(acc[ct][r]);
    }
  }
}

// ---------------- fused accumulate + final GEMM ----------------
// Phase 1 (8 lanes/node, 64 nodes/block, TPB=512): each node's edge list is
// split across two 4-lane half-groups (halved serial gather chain, 2x waves);
// halves combine via __shfl_xor(acc,4). H tile bf16 in XOR-swizzled LDS.
// Phase 2 (waves 0-3): out = H @ W2 + deg*b2 via mfma_f32_16x16x32_bf16.

__global__ __launch_bounds__(512) void accum_final(
    const unsigned char* __restrict__ Af8, const unsigned int* __restrict__ Bpbf,
    const unsigned int* __restrict__ srp, const int* __restrict__ off,
    const int* __restrict__ cnt, const float* __restrict__ W2,
    const float* __restrict__ b2, float* __restrict__ out, int N)
{
  __shared__ __align__(16) unsigned short sW[4 * 2 * 64 * 8];   // 8 KB W2 frags
  __shared__ __align__(16) unsigned short sH[64 * 64];          // 8 KB H tile

  // ---- stage W2 fragments ----
  for (int idx = threadIdx.x; idx < 4096; idx += 512) {
    const int j  = idx & 7;
    const int l  = (idx >> 3) & 63;
    const int ks = (idx >> 9) & 1;
    const int ct = idx >> 10;
    const int k  = ks * 32 + ((l >> 4) << 3) + j;
    const int c  = ct * 16 + (l & 15);
    sW[idx] = f2bf(W2[k * 64 + c]);
  }

  // ---- phase 1: accumulate H for this block's 64 nodes ----
  const int tid = (int)threadIdx.x;
  const int nl  = tid >> 3;            // local node 0..63
  const int h   = (tid >> 2) & 1;      // edge half-group
  const int q   = tid & 3;             // channel quad (16 ch/lane)
  const int n   = blockIdx.x * 64 + nl;
  const bool valid = (n < N);

  int start = 0, deg = 0;
  float bpf[16];
  if (valid) {
    start = off[n];
    deg   = cnt[n];
    const uint4* brow = reinterpret_cast<const uint4*>(Bpbf) + (size_t)n * 8 + q * 2;
    uint4 b0 = brow[0], b1v = brow[1];
    const unsigned int bu[8] = {b0.x, b0.y, b0.z, b0.w, b1v.x, b1v.y, b1v.z, b1v.w};
#pragma unroll
    for (int j = 0; j < 8; ++j) {
      bpf[2 * j]     = __uint_as_float(bu[j] << 16);
      bpf[2 * j + 1] = __uint_as_float(bu[j] & 0xffff0000u);
    }
  } else {
#pragma unroll
    for (int j = 0; j < 16; ++j) bpf[j] = 0.f;
  }

  // split this node's [start, start+deg) across the two half-groups
  const int dh0     = (deg + 1) >> 1;
  const int mystart = start + (h ? dh0 : 0);
  const int mycnt   = h ? (deg - dh0) : dh0;

  float acc[16];
#pragma unroll
  for (int j = 0; j < 16; ++j) acc[j] = 0.f;

  // 4-deep chunks: 4 packed records + 4 independent 16B A-loads in flight
  for (int t0 = 0; t0 < mycnt; t0 += 4) {
    const int rem = mycnt - t0;
    unsigned er[4];
#pragma unroll
    for (int i = 0; i < 4; ++i)
      er[i] = (i < rem) ? srp[mystart + t0 + i] : 0u;

    uint4 Av[4];
#pragma unroll
    for (int i = 0; i < 4; ++i) {
      const size_t row = (size_t)(er[i] >> 15);
      Av[i] = *reinterpret_cast<const uint4*>(Af8 + row * 64 + q * 16);
    }

#pragma unroll
    for (int i = 0; i < 4; ++i) {
      if (i >= rem) break;
      const float eav = (float)(er[i] & 0x7FFFu) * (1.0f / 32767.0f);
      float a[16];
      fp8x4_to_f32(Av[i].x, a);
      fp8x4_to_f32(Av[i].y, a + 4);
      fp8x4_to_f32(Av[i].z, a + 8);
      fp8x4_to_f32(Av[i].w, a + 12);
#pragma unroll
      for (int j = 0; j < 16; ++j)
        acc[j] += fmaxf(fmaf(eav, a[j], bpf[j]), 0.f);
    }
  }

  // combine half-groups (h bit == lane bit 2)
#pragma unroll
  for (int j = 0; j < 16; ++j) acc[j] += __shfl_xor(acc[j], 4);

  // pack 16 fp32 -> bf16, store 2x16B into swizzled LDS row (h==0 only)
  if (h == 0) {
    uint4 h0, h1;
    unsigned int* h0w = &h0.x;
    unsigned int* h1w = &h1.x;
#pragma unroll
    for (int j = 0; j < 4; ++j) {
      h0w[j] = (unsigned int)f2bf(acc[2 * j]) |
               ((unsigned int)f2bf(acc[2 * j + 1]) << 16);
      h1w[j] = (unsigned int)f2bf(acc[8 + 2 * j]) |
               ((unsigned int)f2bf(acc[8 + 2 * j + 1]) << 16);
    }
    const int swz = (nl & 7) << 3;
    *reinterpret_cast<uint4*>(&sH[(nl * 64 + q * 16) ^ swz])     = h0;
    *reinterpret_cast<uint4*>(&sH[(nl * 64 + q * 16 + 8) ^ swz]) = h1;
  }

  __syncthreads();

  // ---- phase 2: out tile = H @ W2 + deg*b2 (waves 0-3 only) ----
  if (tid >= 256) return;
  const int w  = tid >> 6;
  const int l  = tid & 63;
  const int q2 = l >> 4;
  const int m  = l & 15;
  const int n0 = blockIdx.x * 64 + w * 16;
  if (n0 >= N) return;

  short8 bfrag[4][2];
#pragma unroll
  for (int ct = 0; ct < 4; ++ct)
#pragma unroll
    for (int ks = 0; ks < 2; ++ks)
      bfrag[ct][ks] =
          *reinterpret_cast<const short8*>(&sW[(ct * 2 + ks) * 512 + l * 8]);

  const int row = w * 16 + m;                 // LDS row == local node
  const int rswz = (row & 7) << 3;
  short8 afrag[2];
  afrag[0] = *reinterpret_cast<const short8*>(&sH[(row * 64 + q2 * 8) ^ rswz]);
  afrag[1] = *reinterpret_cast<const short8*>(&sH[(row * 64 + 32 + q2 * 8) ^ rswz]);

  float dg[4];
#pragma unroll
  for (int r = 0; r < 4; ++r) {
    const int node = n0 + q2 * 4 + r;
    dg[r] = (node < N) ? (float)cnt[node] : 0.0f;
  }

  f32x4 acc2[4];
#pragma unroll
  for (int ct = 0; ct < 4; ++ct) {
    const float bv = b2[ct * 16 + m];
    acc2[ct] = (f32x4){dg[0] * bv, dg[1] * bv, dg[2] * bv, dg[3] * bv};
  }

#pragma unroll
  for (int ct = 0; ct < 4; ++ct)
#pragma unroll
    for (int ks = 0; ks < 2; ++ks)
      acc2[ct] = __builtin_amdgcn_mfma_f32_16x16x32_bf16(
          afrag[ks], bfrag[ct][ks], acc2[ct], 0, 0, 0);

#pragma unroll
  for (int ct = 0; ct < 4; ++ct) {
    const int ch = ct * 16 + m;
#pragma unroll
    for (int r = 0; r < 4; ++r) {
      const int node = n0 + q2 * 4 + r;
      if (node < N) out[(size_t)node * 64 + ch] = acc2[ct][r];
    }
  }
}

// ---------------- fallback (round-1 path, if ws too small) ----------------

__global__ __launch_bounds__(TPB) void edge_mlp_atomic(
    const float* __restrict__ x, const int* __restrict__ ei,
    const float* __restrict__ eattr, const float* __restrict__ W1,
    const float* __restrict__ b1, const float* __restrict__ W2,
    const float* __restrict__ b2, float* __restrict__ out, int E)
{
  __shared__ float sW1[128 * 64];
  __shared__ float sW2[64 * 64];
  __shared__ float sB1[64];
  __shared__ float sB2[64];
  for (int i = threadIdx.x; i < 128 * 64 / 4; i += TPB)
    reinterpret_cast<float4*>(sW1)[i] = reinterpret_cast<const float4*>(W1)[i];
  for (int i = threadIdx.x; i < 64 * 64 / 4; i += TPB)
    reinterpret_cast<float4*>(sW2)[i] = reinterpret_cast<const float4*>(W2)[i];
  if (threadIdx.x < 64) { sB1[threadIdx.x] = b1[threadIdx.x]; sB2[threadIdx.x] = b2[threadIdx.x]; }
  __syncthreads();
  const int e = blockIdx.x * TPB + (int)threadIdx.x;
  if (e >= E) return;
  const int row = ei[e];
  const int col = ei[E + e];
  const float scale = eattr[e];
  float h[64];
#pragma unroll
  for (int o = 0; o < 64; ++o) h[o] = sB1[o];
#pragma unroll
  for (int half = 0; half < 2; ++half) {
    const float4* src = reinterpret_cast<const float4*>(x + (size_t)(half ? col : row) * 64);
    const float sc = half ? 1.0f : scale;
    const float* wb = sW1 + half * 64 * 64;
    for (int kc = 0; kc < 16; ++kc) {
      float4 cv = src[kc];
      cv.x *= sc; cv.y *= sc; cv.z *= sc; cv.w *= sc;
      const float* wr = wb + kc * 4 * 64;
#pragma unroll
      for (int kk = 0; kk < 4; ++kk) {
        const float c = (&cv.x)[kk];
#pragma unroll
        for (int o = 0; o < 64; ++o) h[o] = fmaf(c, wr[kk * 64 + o], h[o]);
      }
    }
  }
#pragma unroll
  for (int o = 0; o < 64; ++o) h[o] = fmaxf(h[o], 0.0f);
  float* outrow = out + (size_t)col * 64;
#pragma unroll
  for (int oc = 0; oc < 4; ++oc) {
    float m[16];
#pragma unroll
    for (int j = 0; j < 16; ++j) m[j] = sB2[oc * 16 + j];
#pragma unroll
    for (int k = 0; k < 64; ++k) {
      const float hk = h[k];
      const float* wr = sW2 + k * 64 + oc * 16;
#pragma unroll
      for (int j = 0; j < 16; ++j) m[j] = fmaf(hk, wr[j], m[j]);
    }
#pragma unroll
    for (int j = 0; j < 16; ++j) atomicAdd(outrow + oc * 16 + j, m[j]);
  }
}

// ---------------- launch ----------------

extern "C" void kernel_launch(void* const* d_in, const int* in_sizes, int n_in,
                              void* d_out, int out_size, void* d_ws, size_t ws_size,
                              hipStream_t stream) {
  const float* x  = (const float*)d_in[0];
  const int*   ei = (const int*)d_in[1];   // [2,E] int32
  const float* ea = (const float*)d_in[2];
  const float* W1 = (const float*)d_in[3];
  const float* b1 = (const float*)d_in[4];
  const float* W2 = (const float*)d_in[5];
  const float* b2 = (const float*)d_in[6];
  float* out = (float*)d_out;
  const int E = in_sizes[2];
  const int N = in_sizes[0] / 64;

  // ws layout: srp[E] u32 | rank[E] | cnt[N]+total | off[N]
  //            | Af8[N*64 u8] | Bpbf[N*64 u16]
  auto align16 = [](size_t v) { return (v + 15) & ~(size_t)15; };
  size_t o_srp  = 0;
  size_t o_rank = align16(o_srp + (size_t)E * 4);
  size_t o_cnt  = align16(o_rank + (size_t)E * 4);          // cnt + total contiguous
  size_t o_off  = align16(o_cnt + (size_t)(N + 1) * 4);
  size_t o_A    = align16(o_off + (size_t)N * 4);
  size_t o_Bp   = align16(o_A + (size_t)N * 64);
  size_t need   = o_Bp + (size_t)N * 128;

  if (ws_size < need || N > (1 << 17)) {
    hipMemsetAsync(d_out, 0, (size_t)out_size * sizeof(float), stream);
    const int blocks = (E + TPB - 1) / TPB;
    edge_mlp_atomic<<<blocks, TPB, 0, stream>>>(x, ei, ea, W1, b1, W2, b2, out, E);
    return;
  }

  char* ws = (char*)d_ws;
  unsigned int* srp = (unsigned int*)(ws + o_srp);
  int*  rank  = (int*)(ws + o_rank);
  int*  cnt   = (int*)(ws + o_cnt);
  int*  total = cnt + N;
  int*  off   = (int*)(ws + o_off);
  unsigned char*  Af8  = (unsigned char*)(ws + o_A);
  unsigned short* Bpbf = (unsigned short*)(ws + o_Bp);

  hipMemsetAsync(cnt, 0, (size_t)(N + 1) * sizeof(int), stream);

  const int eblocks = (E + TPB - 1) / TPB;
  const int bb = (N + TPB - 1) / TPB;             // base-assign blocks
  const int tblocks = ((N + 15) / 16 + 3) / 4;    // precompute tiles
  const int nb = (N + 63) / 64;                   // accum_final blocks (512 thr)

  hist_rank<<<eblocks, TPB, 0, stream>>>(ei, cnt, rank, E);
  base_and_precompute<<<bb + tblocks, TPB, 0, stream>>>(
      x, W1, b1, cnt, off, total, Af8, Bpbf, N, bb);
  scatter_edges<<<eblocks, TPB, 0, stream>>>(ei, ea, off, rank, srp, E);
  accum_final<<<nb, 512, 0, stream>>>(Af8, (const unsigned int*)Bpbf,
                                      srp, off, cnt, W2, b2, out, N);
}

// Round 6
// 188.129 us; speedup vs baseline: 1.1093x; 1.0432x over previous
//
#include <hip/hip_runtime.h>

// ModularPathwayConv round 16:
//  R15 post-mortem: half-group split NEUTRAL (196.3 vs 194.3) -> accum is
//  random-gather transaction-bound (51MB @ ~1.2TB/s ~= 45us), not chain-bound.
//  Reverted accum to R12 4-lane form.
//  Structural change: CSR build collapsed to ONE kernel via fixed-capacity
//  slotting. pos = col*CAP + atomicAdd(cnt[col]) -- no scan, no off[], no
//  rank[], no second edge pass. CAP=32 (deg~Poisson(8)); correctness for any
//  input via compact overflow list drained by accum_final (expected empty,
//  one cached read per block).
//  4 dispatches: memset -> csr_scatter -> precompute -> accum_final.

constexpr int TPB = 256;
constexpr int CAP = 32;               // slots per node; P(deg>32)~6e-12/node

typedef __attribute__((ext_vector_type(8))) short short8;
typedef __attribute__((ext_vector_type(4))) float f32x4;
typedef __attribute__((ext_vector_type(2))) float f32x2;

// fp32 -> bf16 round-to-nearest-even
__device__ inline unsigned short f2bf(float f) {
  unsigned u = __float_as_uint(f);
  unsigned r = u + 0x7fffu + ((u >> 16) & 1u);
  return (unsigned short)(r >> 16);
}

// ---- fp8 e4m3 encode/decode (HW builtins when available) ----
#if __has_builtin(__builtin_amdgcn_cvt_pk_fp8_f32) && __has_builtin(__builtin_amdgcn_cvt_pk_f32_fp8)
#define FP8_HW 1
#else
#define FP8_HW 0
#endif

__device__ inline unsigned f32_to_fp8(float f) {
#if FP8_HW
  return (unsigned)__builtin_amdgcn_cvt_pk_fp8_f32(f, f, 0, false) & 0xFFu;
#else
  unsigned u = __float_as_uint(f);
  unsigned s = u >> 31;
  float af = fabsf(f);
  if (af >= 448.f) return (s << 7) | 0x7E;
  if (af < 0.015625f) {
    int m = (int)(af * 512.0f + 0.5f);
    if (m > 7) m = 7;
    return (s << 7) | m;
  }
  unsigned r = (u & 0x7FFFFFFFu) + 0x7FFFFu + ((u >> 20) & 1u);
  int e = (int)((r >> 23) & 0xFF) - 127 + 7;
  if (e >= 16) return (s << 7) | 0x7E;
  return (s << 7) | ((unsigned)e << 3) | ((r >> 20) & 7);
#endif
}

// decode 4 fp8 packed in a u32 -> 4 floats
__device__ inline void fp8x4_to_f32(unsigned w, float* o) {
#if FP8_HW
  f32x2 lo = __builtin_amdgcn_cvt_pk_f32_fp8((int)w, false);
  f32x2 hi = __builtin_amdgcn_cvt_pk_f32_fp8((int)w, true);
  o[0] = lo[0]; o[1] = lo[1]; o[2] = hi[0]; o[3] = hi[1];
#else
#pragma unroll
  for (int i = 0; i < 4; ++i) {
    unsigned b = (w >> (8 * i)) & 0xFF;
    unsigned s = (b >> 7) & 1, e = (b >> 3) & 0xF, m = b & 7;
    float v;
    if (e == 0) { v = (float)m * 0.001953125f; v = s ? -v : v; }
    else v = __uint_as_float((s << 31) | ((e - 7 + 127) << 23) | (m << 20));
    o[i] = v;
  }
#endif
}

// ---------------- one-pass CSR build: slot = col*CAP + atomic rank ----------
// 4 edges/thread: 4 independent atomic chains in flight per thread.
// record: (row << 15) | q15(ea).  Overflow (rank>=CAP): compact list.

__global__ __launch_bounds__(TPB) void csr_scatter(
    const int* __restrict__ ei, const float* __restrict__ ea,
    int* __restrict__ cnt, unsigned int* __restrict__ srp,
    uint2* __restrict__ oflow, int* __restrict__ ocnt, int E)
{
  const int base = blockIdx.x * (TPB * 4) + (int)threadIdx.x;
  int   col[4], row[4];
  float eav[4];
  int   r[4];
#pragma unroll
  for (int k = 0; k < 4; ++k) {
    const int e = base + k * TPB;
    if (e < E) { col[k] = ei[E + e]; row[k] = ei[e]; eav[k] = ea[e]; }
    else col[k] = -1;
  }
#pragma unroll
  for (int k = 0; k < 4; ++k)
    if (col[k] >= 0) r[k] = atomicAdd(&cnt[col[k]], 1);
#pragma unroll
  for (int k = 0; k < 4; ++k) {
    if (col[k] < 0) continue;
    unsigned q = (unsigned)(eav[k] * 32767.0f + 0.5f);
    if (q > 32767u) q = 32767u;
    const unsigned rec = ((unsigned)row[k] << 15) | q;
    if (r[k] < CAP) {
      srp[((size_t)col[k] << 5) + r[k]] = rec;
    } else {
      const int oi = atomicAdd(ocnt, 1);
      oflow[oi] = make_uint2(rec, (unsigned)col[k]);
    }
  }
}

// ---------------- precompute MFMA: A = x@W1_top (fp8), Bp = x@W1_bot+b1 ----

__global__ __launch_bounds__(TPB) void precompute_AB(
    const float* __restrict__ x, const float* __restrict__ W1,
    const float* __restrict__ b1,
    unsigned char* __restrict__ Af8, unsigned short* __restrict__ Bpbf, int N)
{
  __shared__ __align__(16) unsigned short sFrag[8 * 2 * 64 * 8];   // 16 KB

  for (int idx = threadIdx.x; idx < 8192; idx += TPB) {
    const int j  = idx & 7;
    const int l  = (idx >> 3) & 63;
    const int ks = (idx >> 9) & 1;
    const int ct = idx >> 10;
    const int k  = ks * 32 + ((l >> 4) << 3) + j;
    const int r  = k + 64 * (ct >> 2);
    const int c  = (ct & 3) * 16 + (l & 15);
    sFrag[idx] = f2bf(W1[r * 64 + c]);
  }
  __syncthreads();

  const int w = threadIdx.x >> 6;
  const int l = threadIdx.x & 63;
  const int q = l >> 4;
  const int m = l & 15;
  const int n0 = ((int)blockIdx.x * 4 + w) * 16;
  if (n0 >= N) return;

  short8 bfrag[8][2];
#pragma unroll
  for (int ct = 0; ct < 8; ++ct)
#pragma unroll
    for (int ks = 0; ks < 2; ++ks)
      bfrag[ct][ks] =
          *reinterpret_cast<const short8*>(&sFrag[(ct * 2 + ks) * 512 + l * 8]);

  const int nA = (n0 + m < N) ? (n0 + m) : (N - 1);
  const float* xr = x + (size_t)nA * 64 + q * 8;
  short8 afrag[2];
#pragma unroll
  for (int ks = 0; ks < 2; ++ks) {
    float4 v0 = *reinterpret_cast<const float4*>(xr + ks * 32);
    float4 v1 = *reinterpret_cast<const float4*>(xr + ks * 32 + 4);
    short8 a;
    a[0] = (short)f2bf(v0.x); a[1] = (short)f2bf(v0.y);
    a[2] = (short)f2bf(v0.z); a[3] = (short)f2bf(v0.w);
    a[4] = (short)f2bf(v1.x); a[5] = (short)f2bf(v1.y);
    a[6] = (short)f2bf(v1.z); a[7] = (short)f2bf(v1.w);
    afrag[ks] = a;
  }

  f32x4 acc[8];
#pragma unroll
  for (int ct = 0; ct < 8; ++ct) {
    const float bv = (ct >= 4) ? b1[(ct - 4) * 16 + m] : 0.0f;
    acc[ct] = (f32x4){bv, bv, bv, bv};
  }

#pragma unroll
  for (int ct = 0; ct < 8; ++ct)
#pragma unroll
    for (int ks = 0; ks < 2; ++ks)
      acc[ct] = __builtin_amdgcn_mfma_f32_16x16x32_bf16(
          afrag[ks], bfrag[ct][ks], acc[ct], 0, 0, 0);

#pragma unroll
  for (int ct = 0; ct < 8; ++ct) {
    const int ch = (ct & 3) * 16 + m;
#pragma unroll
    for (int r = 0; r < 4; ++r) {
      const int node = n0 + q * 4 + r;
      if (node >= N) continue;
      if (ct < 4)
        Af8[(size_t)node * 64 + ch] = (unsigned char)f32_to_fp8(acc[ct][r]);
      else
        Bpbf[(size_t)node * 64 + ch] = f2bf(acc[ct][r]);
    }
  }
}

// ---------------- fused accumulate + final GEMM ----------------
// Phase 1 (4 lanes/node, 64 nodes/block): H[n] = sum relu(ea*A[row]+Bp[n])
// over srp slots [n*CAP, n*CAP+min(cnt,CAP)) + overflow list (usually empty).
// Phase 2: out = H @ W2 + cnt*b2 via mfma on the swizzled LDS H tile.

__global__ __launch_bounds__(TPB) void accum_final(
    const unsigned char* __restrict__ Af8, const unsigned int* __restrict__ Bpbf,
    const unsigned int* __restrict__ srp, const int* __restrict__ cnt,
    const uint2* __restrict__ oflow, const int* __restrict__ ocnt,
    const float* __restrict__ W2, const float* __restrict__ b2,
    float* __restrict__ out, int N)
{
  __shared__ __align__(16) unsigned short sW[4 * 2 * 64 * 8];   // 8 KB W2 frags
  __shared__ __align__(16) unsigned short sH[64 * 64];          // 8 KB H tile

  // ---- stage W2 fragments ----
  for (int idx = threadIdx.x; idx < 4096; idx += TPB) {
    const int j  = idx & 7;
    const int l  = (idx >> 3) & 63;
    const int ks = (idx >> 9) & 1;
    const int ct = idx >> 10;
    const int k  = ks * 32 + ((l >> 4) << 3) + j;
    const int c  = ct * 16 + (l & 15);
    sW[idx] = f2bf(W2[k * 64 + c]);
  }

  // ---- phase 1: accumulate H for this block's 64 nodes ----
  const int tid = (int)threadIdx.x;
  const int nl  = tid >> 2;            // local node 0..63
  const int q   = tid & 3;             // channel quad (16 ch/lane)
  const int n   = blockIdx.x * 64 + nl;
  const bool valid = (n < N);

  int deg = 0;
  float bpf[16];
  if (valid) {
    deg = cnt[n];
    const uint4* brow = reinterpret_cast<const uint4*>(Bpbf) + (size_t)n * 8 + q * 2;
    uint4 b0 = brow[0], b1v = brow[1];
    const unsigned int bu[8] = {b0.x, b0.y, b0.z, b0.w, b1v.x, b1v.y, b1v.z, b1v.w};
#pragma unroll
    for (int j = 0; j < 8; ++j) {
      bpf[2 * j]     = __uint_as_float(bu[j] << 16);
      bpf[2 * j + 1] = __uint_as_float(bu[j] & 0xffff0000u);
    }
  } else {
#pragma unroll
    for (int j = 0; j < 16; ++j) bpf[j] = 0.f;
  }

  const int start = n << 5;                         // n*CAP
  const int mdeg  = (deg < CAP) ? deg : CAP;

  float acc[16];
#pragma unroll
  for (int j = 0; j < 16; ++j) acc[j] = 0.f;

  // 4-deep chunks: 4 packed records + 4 independent 16B A-loads in flight
  for (int t0 = 0; t0 < mdeg; t0 += 4) {
    const int rem = mdeg - t0;
    unsigned er[4];
#pragma unroll
    for (int i = 0; i < 4; ++i)
      er[i] = (i < rem) ? srp[start + t0 + i] : 0u;

    uint4 Av[4];
#pragma unroll
    for (int i = 0; i < 4; ++i) {
      const size_t row = (size_t)(er[i] >> 15);
      Av[i] = *reinterpret_cast<const uint4*>(Af8 + row * 64 + q * 16);
    }

#pragma unroll
    for (int i = 0; i < 4; ++i) {
      if (i >= rem) break;
      const float eav = (float)(er[i] & 0x7FFFu) * (1.0f / 32767.0f);
      float a[16];
      fp8x4_to_f32(Av[i].x, a);
      fp8x4_to_f32(Av[i].y, a + 4);
      fp8x4_to_f32(Av[i].z, a + 8);
      fp8x4_to_f32(Av[i].w, a + 12);
#pragma unroll
      for (int j = 0; j < 16; ++j)
        acc[j] += fmaxf(fmaf(eav, a[j], bpf[j]), 0.f);
    }
  }

  // ---- overflow drain (expected empty; one cached read per block) ----
  const int oc = *ocnt;
  for (int i = 0; i < oc; ++i) {
    const uint2 oe = oflow[i];
    if (!valid || (int)oe.y != n) continue;
    const size_t row = (size_t)(oe.x >> 15);
    const float eav  = (float)(oe.x & 0x7FFFu) * (1.0f / 32767.0f);
    const uint4 Av = *reinterpret_cast<const uint4*>(Af8 + row * 64 + q * 16);
    float a[16];
    fp8x4_to_f32(Av.x, a);
    fp8x4_to_f32(Av.y, a + 4);
    fp8x4_to_f32(Av.z, a + 8);
    fp8x4_to_f32(Av.w, a + 12);
#pragma unroll
    for (int j = 0; j < 16; ++j)
      acc[j] += fmaxf(fmaf(eav, a[j], bpf[j]), 0.f);
  }

  // pack 16 fp32 -> bf16, store 2x16B into swizzled LDS row
  {
    uint4 h0, h1;
    unsigned int* h0w = &h0.x;
    unsigned int* h1w = &h1.x;
#pragma unroll
    for (int j = 0; j < 4; ++j) {
      h0w[j] = (unsigned int)f2bf(acc[2 * j]) |
               ((unsigned int)f2bf(acc[2 * j + 1]) << 16);
      h1w[j] = (unsigned int)f2bf(acc[8 + 2 * j]) |
               ((unsigned int)f2bf(acc[8 + 2 * j + 1]) << 16);
    }
    const int swz = (nl & 7) << 3;
    *reinterpret_cast<uint4*>(&sH[(nl * 64 + q * 16) ^ swz])     = h0;
    *reinterpret_cast<uint4*>(&sH[(nl * 64 + q * 16 + 8) ^ swz]) = h1;
  }

  __syncthreads();

  // ---- phase 2: out tile = H @ W2 + cnt*b2 (wave w -> 16-node subtile) ----
  const int w  = tid >> 6;
  const int l  = tid & 63;
  const int q2 = l >> 4;
  const int m  = l & 15;
  const int n0 = blockIdx.x * 64 + w * 16;
  if (n0 >= N) return;

  short8 bfrag[4][2];
#pragma unroll
  for (int ct = 0; ct < 4; ++ct)
#pragma unroll
    for (int ks = 0; ks < 2; ++ks)
      bfrag[ct][ks] =
          *reinterpret_cast<const short8*>(&sW[(ct * 2 + ks) * 512 + l * 8]);

  const int row = w * 16 + m;                 // LDS row == local node
  const int rswz = (row & 7) << 3;
  short8 afrag[2];
  afrag[0] = *reinterpret_cast<const short8*>(&sH[(row * 64 + q2 * 8) ^ rswz]);
  afrag[1] = *reinterpret_cast<const short8*>(&sH[(row * 64 + 32 + q2 * 8) ^ rswz]);

  float dg[4];
#pragma unroll
  for (int r = 0; r < 4; ++r) {
    const int node = n0 + q2 * 4 + r;
    dg[r] = (node < N) ? (float)cnt[node] : 0.0f;
  }

  f32x4 acc2[4];
#pragma unroll
  for (int ct = 0; ct < 4; ++ct) {
    const float bv = b2[ct * 16 + m];
    acc2[ct] = (f32x4){dg[0] * bv, dg[1] * bv, dg[2] * bv, dg[3] * bv};
  }

#pragma unroll
  for (int ct = 0; ct < 4; ++ct)
#pragma unroll
    for (int ks = 0; ks < 2; ++ks)
      acc2[ct] = __builtin_amdgcn_mfma_f32_16x16x32_bf16(
          afrag[ks], bfrag[ct][ks], acc2[ct], 0, 0, 0);

#pragma unroll
  for (int ct = 0; ct < 4; ++ct) {
    const int ch = ct * 16 + m;
#pragma unroll
    for (int r = 0; r < 4; ++r) {
      const int node = n0 + q2 * 4 + r;
      if (node < N) out[(size_t)node * 64 + ch] = acc2[ct][r];
    }
  }
}

// ---------------- fallback (round-1 path, if ws too small) ----------------

__global__ __launch_bounds__(TPB) void edge_mlp_atomic(
    const float* __restrict__ x, const int* __restrict__ ei,
    const float* __restrict__ eattr, const float* __restrict__ W1,
    const float* __restrict__ b1, const float* __restrict__ W2,
    const float* __restrict__ b2, float* __restrict__ out, int E)
{
  __shared__ float sW1[128 * 64];
  __shared__ float sW2[64 * 64];
  __shared__ float sB1[64];
  __shared__ float sB2[64];
  for (int i = threadIdx.x; i < 128 * 64 / 4; i += TPB)
    reinterpret_cast<float4*>(sW1)[i] = reinterpret_cast<const float4*>(W1)[i];
  for (int i = threadIdx.x; i < 64 * 64 / 4; i += TPB)
    reinterpret_cast<float4*>(sW2)[i] = reinterpret_cast<const float4*>(W2)[i];
  if (threadIdx.x < 64) { sB1[threadIdx.x] = b1[threadIdx.x]; sB2[threadIdx.x] = b2[threadIdx.x]; }
  __syncthreads();
  const int e = blockIdx.x * TPB + (int)threadIdx.x;
  if (e >= E) return;
  const int row = ei[e];
  const int col = ei[E + e];
  const float scale = eattr[e];
  float h[64];
#pragma unroll
  for (int o = 0; o < 64; ++o) h[o] = sB1[o];
#pragma unroll
  for (int half = 0; half < 2; ++half) {
    const float4* src = reinterpret_cast<const float4*>(x + (size_t)(half ? col : row) * 64);
    const float sc = half ? 1.0f : scale;
    const float* wb = sW1 + half * 64 * 64;
    for (int kc = 0; kc < 16; ++kc) {
      float4 cv = src[kc];
      cv.x *= sc; cv.y *= sc; cv.z *= sc; cv.w *= sc;
      const float* wr = wb + kc * 4 * 64;
#pragma unroll
      for (int kk = 0; kk < 4; ++kk) {
        const float c = (&cv.x)[kk];
#pragma unroll
        for (int o = 0; o < 64; ++o) h[o] = fmaf(c, wr[kk * 64 + o], h[o]);
      }
    }
  }
#pragma unroll
  for (int o = 0; o < 64; ++o) h[o] = fmaxf(h[o], 0.0f);
  float* outrow = out + (size_t)col * 64;
#pragma unroll
  for (int oc = 0; oc < 4; ++oc) {
    float m[16];
#pragma unroll
    for (int j = 0; j < 16; ++j) m[j] = sB2[oc * 16 + j];
#pragma unroll
    for (int k = 0; k < 64; ++k) {
      const float hk = h[k];
      const float* wr = sW2 + k * 64 + oc * 16;
#pragma unroll
      for (int j = 0; j < 16; ++j) m[j] = fmaf(hk, wr[j], m[j]);
    }
#pragma unroll
    for (int j = 0; j < 16; ++j) atomicAdd(outrow + oc * 16 + j, m[j]);
  }
}

// ---------------- launch ----------------

extern "C" void kernel_launch(void* const* d_in, const int* in_sizes, int n_in,
                              void* d_out, int out_size, void* d_ws, size_t ws_size,
                              hipStream_t stream) {
  const float* x  = (const float*)d_in[0];
  const int*   ei = (const int*)d_in[1];   // [2,E] int32
  const float* ea = (const float*)d_in[2];
  const float* W1 = (const float*)d_in[3];
  const float* b1 = (const float*)d_in[4];
  const float* W2 = (const float*)d_in[5];
  const float* b2 = (const float*)d_in[6];
  float* out = (float*)d_out;
  const int E = in_sizes[2];
  const int N = in_sizes[0] / 64;

  // ws layout: srp[N*CAP] u32 | cnt[N]+ocnt | oflow[E] uint2
  //            | Af8[N*64 u8] | Bpbf[N*64 u16]
  auto align16 = [](size_t v) { return (v + 15) & ~(size_t)15; };
  size_t o_srp  = 0;
  size_t o_cnt  = align16(o_srp + (size_t)N * CAP * 4);
  size_t o_ofl  = align16(o_cnt + (size_t)(N + 1) * 4);     // cnt + ocnt contiguous
  size_t o_A    = align16(o_ofl + (size_t)E * 8);
  size_t o_Bp   = align16(o_A + (size_t)N * 64);
  size_t need   = o_Bp + (size_t)N * 128;

  if (ws_size < need || N > (1 << 17)) {
    hipMemsetAsync(d_out, 0, (size_t)out_size * sizeof(float), stream);
    const int blocks = (E + TPB - 1) / TPB;
    edge_mlp_atomic<<<blocks, TPB, 0, stream>>>(x, ei, ea, W1, b1, W2, b2, out, E);
    return;
  }

  char* ws = (char*)d_ws;
  unsigned int* srp = (unsigned int*)(ws + o_srp);
  int*   cnt  = (int*)(ws + o_cnt);
  int*   ocnt = cnt + N;
  uint2* ofl  = (uint2*)(ws + o_ofl);
  unsigned char*  Af8  = (unsigned char*)(ws + o_A);
  unsigned short* Bpbf = (unsigned short*)(ws + o_Bp);

  hipMemsetAsync(cnt, 0, (size_t)(N + 1) * sizeof(int), stream);

  const int cblocks = (E + TPB * 4 - 1) / (TPB * 4);  // csr_scatter (4 e/thr)
  const int tblocks = ((N + 15) / 16 + 3) / 4;        // precompute tiles
  const int nb = (N + 63) / 64;                       // accum_final blocks

  csr_scatter<<<cblocks, TPB, 0, stream>>>(ei, ea, cnt, srp, ofl, ocnt, E);
  precompute_AB<<<tblocks, TPB, 0, stream>>>(x, W1, b1, Af8, Bpbf, N);
  accum_final<<<nb, TPB, 0, stream>>>(Af8, (const unsigned int*)Bpbf,
                                      srp, cnt, ofl, ocnt, W2, b2, out, N);
}